// Round 9
// baseline (355.660 us; speedup 1.0000x reference)
//
#include <hip/hip_runtime.h>
#include <math.h>

#define SEQ 4096
#define DM  1024
#define NH  16
#define DH  64
#define NS  4      // k-splits per q-tile

typedef _Float16 h16;
typedef __attribute__((ext_vector_type(4))) _Float16 h16x4;
typedef __attribute__((ext_vector_type(8))) _Float16 h16x8;
typedef __attribute__((ext_vector_type(4))) float f32x4;

// async global->LDS, 16B per lane, dest = wave-uniform base + lane*16
__device__ __forceinline__ void gload_lds16(const h16* g, h16* l) {
    __builtin_amdgcn_global_load_lds(
        (const __attribute__((address_space(1))) void*)g,
        (__attribute__((address_space(3))) void*)l, 16, 0, 0);
}

// ---------------------------------------------------------------------------
// Single fused fp32 -> fp16 conversion for x + all 4 weights.
// ---------------------------------------------------------------------------
__global__ __launch_bounds__(256) void cvt_all(const float* __restrict__ x,
                                               const float* __restrict__ wq,
                                               const float* __restrict__ wk,
                                               const float* __restrict__ wv,
                                               const float* __restrict__ wo,
                                               h16* __restrict__ dst) {
    const size_t SD4 = (size_t)SEQ * DM / 4;   // 1M float4s
    const size_t DD4 = (size_t)DM * DM / 4;    // 256K float4s
    const size_t i = (size_t)blockIdx.x * 256 + threadIdx.x;
    const float* src;
    size_t off;
    if (i < SD4) { src = x; off = i; }
    else {
        const size_t j = i - SD4;
        const int wsel = (int)(j >> 18);       // DD4 = 2^18
        off = j & (DD4 - 1);
        src = (wsel == 0) ? wq : (wsel == 1) ? wk : (wsel == 2) ? wv : wo;
    }
    const float4 v = ((const float4*)src)[off];
    h16x4 o = { (h16)v.x, (h16)v.y, (h16)v.z, (h16)v.w };
    ((h16x4*)dst)[i] = o;
}

// ---------------------------------------------------------------------------
// m97-style MFMA GEMM: 128x128 tile, BK=64 (two 32-slabs), global_load_lds
// width-16 staging into unpadded GT=32 layout. 4 waves, 4x4 frags.
// Layouts: Q/K plain [SEQ][DM] (scaled Q), V^T [DM][SEQ].
// ---------------------------------------------------------------------------
#define GT 32

// z = 0,1,2 -> Q (scaled), K, V^T outputs
__global__ __launch_bounds__(256) void gemm_qkv(const h16* __restrict__ xh,
                                                const h16* __restrict__ Wq,
                                                const h16* __restrict__ Wk,
                                                const h16* __restrict__ Wv,
                                                h16* __restrict__ Qh,
                                                h16* __restrict__ Kh,
                                                h16* __restrict__ Vth,
                                                float scl) {
    __shared__ h16 As[2][128 * GT];
    __shared__ h16 Bs[2][128 * GT];

    const int z    = blockIdx.z;
    const h16* B   = (z == 0) ? Wq : (z == 1) ? Wk : Wv;
    const int t    = threadIdx.x;
    const int lane = t & 63;
    const int w    = t >> 6;
    const int wm   = (w >> 1) * 64;
    const int wn   = (w & 1) * 64;
    const int l15  = lane & 15;
    const int lq   = lane >> 4;
    const int lq8  = lq * 8;
    const int m0   = blockIdx.y * 128;
    const int n0   = blockIdx.x * 128;
    const int K = DM, M = SEQ, N = DM;

    const int srow = w * 16 + (lane >> 2);
    const int scol = (lane & 3) * 8;
    const h16* pa0 = xh + (size_t)(m0 + srow) * K + scol;
    const h16* pa1 = xh + (size_t)(m0 + 64 + srow) * K + scol;
    const h16* pb0 = B  + (size_t)(n0 + srow) * K + scol;
    const h16* pb1 = B  + (size_t)(n0 + 64 + srow) * K + scol;

    f32x4 acc[4][4] = {};

    for (int k0 = 0; k0 < K; k0 += 64) {
        __syncthreads();
        #pragma unroll
        for (int s = 0; s < 2; ++s) {
            const int ko = k0 + s * 32;
            gload_lds16(pa0 + ko, &As[s][w * 512]);
            gload_lds16(pa1 + ko, &As[s][2048 + w * 512]);
            gload_lds16(pb0 + ko, &Bs[s][w * 512]);
            gload_lds16(pb1 + ko, &Bs[s][2048 + w * 512]);
        }
        __syncthreads();

        #pragma unroll
        for (int s = 0; s < 2; ++s) {
            h16x8 af[4], bf[4];
            #pragma unroll
            for (int i = 0; i < 4; ++i)
                af[i] = *(const h16x8*)&As[s][(wm + i * 16 + l15) * GT + lq8];
            #pragma unroll
            for (int j = 0; j < 4; ++j)
                bf[j] = *(const h16x8*)&Bs[s][(wn + j * 16 + l15) * GT + lq8];
            #pragma unroll
            for (int i = 0; i < 4; ++i)
                #pragma unroll
                for (int j = 0; j < 4; ++j)
                    acc[i][j] = __builtin_amdgcn_mfma_f32_16x16x32_f16(af[i], bf[j], acc[i][j], 0, 0, 0);
        }
    }

    const int cr = wm + lq * 4;
    const int cc = wn + l15;
    if (z == 2) {   // V^T: h16 [N][M], vectorized along M
        #pragma unroll
        for (int i = 0; i < 4; ++i)
            #pragma unroll
            for (int j = 0; j < 4; ++j) {
                const int gm0 = m0 + cr + i * 16;
                const int gn  = n0 + cc + j * 16;
                h16x4 v = { (h16)acc[i][j][0], (h16)acc[i][j][1],
                            (h16)acc[i][j][2], (h16)acc[i][j][3] };
                *(h16x4*)(Vth + (size_t)gn * M + gm0) = v;
            }
    } else {
        h16* Og = (z == 0) ? Qh : Kh;
        const float e = (z == 0) ? scl : 1.0f;
        #pragma unroll
        for (int i = 0; i < 4; ++i)
            #pragma unroll
            for (int j = 0; j < 4; ++j)
                #pragma unroll
                for (int r = 0; r < 4; ++r) {
                    const int gm = m0 + cr + i * 16 + r;
                    const int gn = n0 + cc + j * 16;
                    Og[(size_t)gm * N + gn] = (h16)(acc[i][j][r] * e);
                }
    }
}

// out[M][N] (f32) = AO (h16) @ Wo^T (h16). 64x128 tile -> grid 512 = 2/CU.
__global__ __launch_bounds__(256) void gemm_out(const h16* __restrict__ A,
                                                const h16* __restrict__ B,
                                                float* __restrict__ C) {
    __shared__ h16 As[2][64 * GT];
    __shared__ h16 Bs[2][128 * GT];

    const int t    = threadIdx.x;
    const int lane = t & 63;
    const int w    = t >> 6;
    const int wm   = (w >> 1) * 32;
    const int wn   = (w & 1) * 64;
    const int l15  = lane & 15;
    const int lq   = lane >> 4;
    const int lq8  = lq * 8;
    const int m0   = blockIdx.y * 64;
    const int n0   = blockIdx.x * 128;
    const int K = DM, N = DM;

    const int srow = w * 16 + (lane >> 2);
    const int scol = (lane & 3) * 8;
    const h16* pa0 = A + (size_t)(m0 + srow) * K + scol;
    const h16* pb0 = B + (size_t)(n0 + srow) * K + scol;
    const h16* pb1 = B + (size_t)(n0 + 64 + srow) * K + scol;

    f32x4 acc[2][4] = {};

    for (int k0 = 0; k0 < K; k0 += 64) {
        __syncthreads();
        #pragma unroll
        for (int s = 0; s < 2; ++s) {
            const int ko = k0 + s * 32;
            gload_lds16(pa0 + ko, &As[s][w * 512]);
            gload_lds16(pb0 + ko, &Bs[s][w * 512]);
            gload_lds16(pb1 + ko, &Bs[s][2048 + w * 512]);
        }
        __syncthreads();

        #pragma unroll
        for (int s = 0; s < 2; ++s) {
            h16x8 af[2], bf[4];
            #pragma unroll
            for (int i = 0; i < 2; ++i)
                af[i] = *(const h16x8*)&As[s][(wm + i * 16 + l15) * GT + lq8];
            #pragma unroll
            for (int j = 0; j < 4; ++j)
                bf[j] = *(const h16x8*)&Bs[s][(wn + j * 16 + l15) * GT + lq8];
            #pragma unroll
            for (int i = 0; i < 2; ++i)
                #pragma unroll
                for (int j = 0; j < 4; ++j)
                    acc[i][j] = __builtin_amdgcn_mfma_f32_16x16x32_f16(af[i], bf[j], acc[i][j], 0, 0, 0);
        }
    }

    const int cr = wm + lq * 4;
    const int cc = wn + l15;
    #pragma unroll
    for (int i = 0; i < 2; ++i)
        #pragma unroll
        for (int j = 0; j < 4; ++j)
            #pragma unroll
            for (int r = 0; r < 4; ++r)
                C[(size_t)(m0 + cr + i * 16 + r) * N + n0 + cc + j * 16] = acc[i][j][r];
}

// ---------------------------------------------------------------------------
// SPLIT-K MFMA flash attention (causal), S^T formulation, exp2 domain.
// THIS ROUND: NO LDS, NO BARRIERS. Per-head K/V (512KB each) is L2-resident
// (FETCH counters prove 90% L2 absorption) -> kf/vf fragments load directly
// from global to registers (addresses identical to the old LDS values).
// Waves are fully decoupled: the 8-round-invariant co-stall (barrier
// lockstep x serial shfl chain) is structurally removed.
//  - K fragments: 2-deep A/B register sets, unroll-by-2 loop (static idx).
//  - V fragments: issued at iteration start, consumed after softmax
//    (~500 cycles of cover vs ~200-400 cyc L2 latency).
//  - softmax: per-lane 16-max tree + __all gate skips the 2 shfls AND the
//    rescale in the steady state (provably identical numerics).
// ---------------------------------------------------------------------------
__device__ __forceinline__ void attn_step(
        int kt, bool pref,
        const h16* __restrict__ Kg, const h16* __restrict__ Vt,
        int l15, int lq, int lq8, int hc, int q0, int qa,
        int diag1, int diag2,
        h16x8 (&cur)[2][4], h16x8 (&nxt)[2][4],
        h16x8 (&qf)[2][2],
        float (&m_st)[2], float (&l_st)[2], f32x4 (&o)[2][4]) {
    // V fragments for THIS tile: issue first (consumed after softmax)
    h16x4 vf[4][4];
    #pragma unroll
    for (int dd = 0; dd < 4; ++dd)
        #pragma unroll
        for (int jj = 0; jj < 4; ++jj)
            vf[dd][jj] = *(const h16x4*)(Vt + (size_t)(hc + dd * 16 + l15) * SEQ
                                         + kt * 64 + jj * 16 + lq * 4);
    // prefetch NEXT tile's K fragments (consumed next step; full step of cover)
    if (pref) {
        #pragma unroll
        for (int kc = 0; kc < 2; ++kc)
            #pragma unroll
            for (int jj = 0; jj < 4; ++jj)
                nxt[kc][jj] = *(const h16x8*)(Kg + (size_t)((kt + 1) * 64 + jj * 16 + l15) * DM
                                              + hc + kc * 32 + lq8);
    }

    // ---- S^T = K Q^T for both q-halves (kf from registers) ----
    f32x4 s[2][4] = {};
    #pragma unroll
    for (int kc = 0; kc < 2; ++kc)
        #pragma unroll
        for (int jj = 0; jj < 4; ++jj) {
            s[0][jj] = __builtin_amdgcn_mfma_f32_16x16x32_f16(cur[kc][jj], qf[0][kc], s[0][jj], 0, 0, 0);
            s[1][jj] = __builtin_amdgcn_mfma_f32_16x16x32_f16(cur[kc][jj], qf[1][kc], s[1][jj], 0, 0, 0);
        }

    // ---- causal masks (block-uniform outer branches) ----
    if (kt >= diag1) {
        const int rel = (q0 + qa) - kt * 64;
        #pragma unroll
        for (int jj = 0; jj < 4; ++jj)
            #pragma unroll
            for (int r = 0; r < 4; ++r)
                if ((jj * 16 + lq * 4 + r) > rel) s[0][jj][r] = -1e30f;
    }
    if (kt >= diag2) {
        const int rel = (q0 + 64 + qa) - kt * 64;
        #pragma unroll
        for (int jj = 0; jj < 4; ++jj)
            #pragma unroll
            for (int r = 0; r < 4; ++r)
                if ((jj * 16 + lq * 4 + r) > rel) s[1][jj][r] = -1e30f;
    }

    // ---- online softmax; shfl-skip via per-lane max + __all gate ----
    h16x4 pk[2][4];
    #pragma unroll
    for (int h = 0; h < 2; ++h) {
        const float a0 = fmaxf(fmaxf(s[h][0][0], s[h][0][1]), fmaxf(s[h][0][2], s[h][0][3]));
        const float a1 = fmaxf(fmaxf(s[h][1][0], s[h][1][1]), fmaxf(s[h][1][2], s[h][1][3]));
        const float a2 = fmaxf(fmaxf(s[h][2][0], s[h][2][1]), fmaxf(s[h][2][2], s[h][2][3]));
        const float a3 = fmaxf(fmaxf(s[h][3][0], s[h][3][1]), fmaxf(s[h][3][2], s[h][3][3]));
        const float mxl = fmaxf(fmaxf(a0, a1), fmaxf(a2, a3));
        // steady state: every lane's 16 scores <= m_st+5 -> skip shfls+rescale
        if (!__all(mxl <= m_st[h] + 5.0f)) {
            float mx = fmaxf(mxl, __shfl_xor(mxl, 16, 64));
            mx = fmaxf(mx, __shfl_xor(mx, 32, 64));
            if (mx > m_st[h] + 5.0f) {   // per-row (uniform over a row's 4 lanes)
                const float alpha = exp2f(m_st[h] - mx);
                m_st[h] = mx;
                l_st[h] *= alpha;
                #pragma unroll
                for (int jj = 0; jj < 4; ++jj)
                    #pragma unroll
                    for (int r = 0; r < 4; ++r)
                        o[h][jj][r] *= alpha;
            }
        }
        #pragma unroll
        for (int jj = 0; jj < 4; ++jj) {
            const float p0 = exp2f(s[h][jj][0] - m_st[h]);
            const float p1 = exp2f(s[h][jj][1] - m_st[h]);
            const float p2 = exp2f(s[h][jj][2] - m_st[h]);
            const float p3 = exp2f(s[h][jj][3] - m_st[h]);
            l_st[h] += (p0 + p1) + (p2 + p3);
            pk[h][jj] = h16x4{ (h16)p0, (h16)p1, (h16)p2, (h16)p3 };
        }
    }

    // ---- O^T += V^T P^T (16x16x16 MFMA; vf shared by both halves) ----
    #pragma unroll
    for (int dd = 0; dd < 4; ++dd)
        #pragma unroll
        for (int jj = 0; jj < 4; ++jj) {
            o[0][dd] = __builtin_amdgcn_mfma_f32_16x16x16f16(vf[dd][jj], pk[0][jj], o[0][dd], 0, 0, 0);
            o[1][dd] = __builtin_amdgcn_mfma_f32_16x16x16f16(vf[dd][jj], pk[1][jj], o[1][dd], 0, 0, 0);
        }
}

__global__ __launch_bounds__(256, 2) void flash_attn_split(
        const h16* __restrict__ Qg, const h16* __restrict__ Kg,
        const h16* __restrict__ Vt, h16* __restrict__ OP,
        float* __restrict__ Mb, float* __restrict__ Lb) {
    const int jq   = 31 - (int)blockIdx.y;   // big chunks dispatch first
    const int hh   = blockIdx.x;
    const int sp   = blockIdx.z;
    const int t    = threadIdx.x;
    const int lane = t & 63;
    const int w    = t >> 6;
    const int l15  = lane & 15;
    const int lq   = lane >> 4;
    const int lq8  = lq * 8;
    const int hc   = hh * DH;
    const int q0   = jq * 128;
    const int qa   = w * 16 + l15;           // local q within each 64-half
    const int diag1 = 2 * jq;                // diagonal k-tile of half 1
    const int diag2 = 2 * jq + 1;            // diagonal k-tile of half 2

    const int ntile = 2 * jq + 2;
    const int chunk = (ntile + NS - 1) / NS;
    const int kts   = sp * chunk;
    const int kte   = (kts + chunk < ntile) ? (kts + chunk) : ntile;

    // Q fragments for both halves: direct global reads (one-time per block)
    const size_t qrow1 = (size_t)(q0 + qa) * DM + hc;
    const size_t qrow2 = (size_t)(q0 + 64 + qa) * DM + hc;
    h16x8 qf[2][2];
    qf[0][0] = *(const h16x8*)(Qg + qrow1 + lq8);
    qf[0][1] = *(const h16x8*)(Qg + qrow1 + 32 + lq8);
    qf[1][0] = *(const h16x8*)(Qg + qrow2 + lq8);
    qf[1][1] = *(const h16x8*)(Qg + qrow2 + 32 + lq8);

    float m_st[2] = { -1e30f, -1e30f };
    float l_st[2] = { 0.0f, 0.0f };      // PER-LANE partial sums
    f32x4 o[2][4] = {};

    h16x8 kfA[2][4], kfB[2][4];
    if (kts < kte) {   // preload K fragments of tile kts -> set A
        #pragma unroll
        for (int kc = 0; kc < 2; ++kc)
            #pragma unroll
            for (int jj = 0; jj < 4; ++jj)
                kfA[kc][jj] = *(const h16x8*)(Kg + (size_t)(kts * 64 + jj * 16 + l15) * DM
                                              + hc + kc * 32 + lq8);
    }

    int kt = kts;
    for (; kt + 1 < kte; kt += 2) {
        attn_step(kt,     true,            Kg, Vt, l15, lq, lq8, hc, q0, qa,
                  diag1, diag2, kfA, kfB, qf, m_st, l_st, o);
        attn_step(kt + 1, (kt + 2 < kte),  Kg, Vt, l15, lq, lq8, hc, q0, qa,
                  diag1, diag2, kfB, kfA, qf, m_st, l_st, o);
    }
    if (kt < kte)
        attn_step(kt, false, Kg, Vt, l15, lq, lq8, hc, q0, qa,
                  diag1, diag2, kfA, kfB, qf, m_st, l_st, o);

    // fold the per-lane partial sums (q-row spread over 4 lanes via lq)
    #pragma unroll
    for (int h = 0; h < 2; ++h) {
        l_st[h] += __shfl_xor(l_st[h], 16, 64);
        l_st[h] += __shfl_xor(l_st[h], 32, 64);
    }

    // ---- epilogue: write UNNORMALIZED partial O + (m, l), both halves ----
    h16* const op = OP + (size_t)sp * SEQ * DM;
    #pragma unroll
    for (int h = 0; h < 2; ++h) {
        const int qg_row = q0 + h * 64 + qa;
        const size_t qg = (size_t)qg_row * DM + hc;
        #pragma unroll
        for (int jj = 0; jj < 4; ++jj) {
            h16x4 ov = { (h16)o[h][jj][0], (h16)o[h][jj][1],
                         (h16)o[h][jj][2], (h16)o[h][jj][3] };
            *(h16x4*)(op + qg + jj * 16 + lq * 4) = ov;
        }
        if (lq == 0) {   // one lane per q-row (all lq agree after the fold)
            const size_t mi = ((size_t)sp * NH + hh) * SEQ + qg_row;
            Mb[mi] = m_st[h];
            Lb[mi] = l_st[h];
        }
    }
}

// ---------------------------------------------------------------------------
// Combine NS partials: O = sum_s w_s*O_s / sum_s w_s*l_s, w_s = exp2(m_s-m*).
// One thread per 4 d-columns of one q-row.
// ---------------------------------------------------------------------------
__global__ __launch_bounds__(256) void combine(const h16* __restrict__ OP,
                                               const float* __restrict__ Mb,
                                               const float* __restrict__ Lb,
                                               h16* __restrict__ AOh) {
    const int i  = blockIdx.x * 256 + threadIdx.x;   // 1M threads
    const int q  = i >> 8;
    const int c4 = (i & 255) * 4;
    const int hh = c4 >> 6;

    float ms[NS], ls[NS];
    float mstar = -1e30f;
    #pragma unroll
    for (int s = 0; s < NS; ++s) {
        const size_t mi = ((size_t)s * NH + hh) * SEQ + q;
        ms[s] = Mb[mi];
        ls[s] = Lb[mi];
        mstar = fmaxf(mstar, ms[s]);
    }
    float L = 0.0f;
    float acc[4] = {};
    #pragma unroll
    for (int s = 0; s < NS; ++s) {
        const float ws = exp2f(ms[s] - mstar);
        L += ls[s] * ws;
        const h16x4 ov = *(const h16x4*)(OP + (size_t)s * SEQ * DM + (size_t)q * DM + c4);
        acc[0] += ws * (float)ov[0];
        acc[1] += ws * (float)ov[1];
        acc[2] += ws * (float)ov[2];
        acc[3] += ws * (float)ov[3];
    }
    const float inv = 1.0f / L;
    h16x4 r = { (h16)(acc[0] * inv), (h16)(acc[1] * inv),
                (h16)(acc[2] * inv), (h16)(acc[3] * inv) };
    *(h16x4*)(AOh + (size_t)q * DM + c4) = r;
}

// ---------------------------------------------------------------------------
extern "C" void kernel_launch(void* const* d_in, const int* in_sizes, int n_in,
                              void* d_out, int out_size, void* d_ws, size_t ws_size,
                              hipStream_t stream) {
    const float* x  = (const float*)d_in[0];
    const float* Wq = (const float*)d_in[1];
    const float* Wk = (const float*)d_in[2];
    const float* Wv = (const float*)d_in[3];
    const float* Wo = (const float*)d_in[4];
    float* out = (float*)d_out;

    const size_t SD = (size_t)SEQ * DM;   // 4M
    const size_t DD = (size_t)DM * DM;    // 1M

    h16* xh  = (h16*)d_ws;                // cvt_all relies on this contiguity
    h16* wqh = xh + SD;
    h16* wkh = wqh + DD;
    h16* wvh = wkh + DD;
    h16* woh = wvh + DD;
    h16* Qh  = woh + DD;
    h16* Kh  = Qh + SD;
    h16* Vth = Kh + SD;                   // transposed: [DM][SEQ]
    h16* AOh = Vth + SD;
    h16* OP  = AOh + SD;                  // NS partial O buffers
    float* Mb = (float*)(OP + (size_t)NS * SD);
    float* Lb = Mb + (size_t)NS * NH * SEQ;

    const dim3 blk(256);

    cvt_all<<<(int)((SD + 4 * DD) / 4 / 256), blk, 0, stream>>>(x, Wq, Wk, Wv, Wo, xh);

    // Q pre-scaled by 1/sqrt(DH) * log2(e) for the exp2-domain softmax
    const float SCL = 0.125f * 1.44269504088896340736f;

    gemm_qkv<<<dim3(DM / 128, SEQ / 128, 3), blk, 0, stream>>>(
        xh, wqh, wkh, wvh, Qh, Kh, Vth, SCL);

    flash_attn_split<<<dim3(NH, 32, NS), blk, 0, stream>>>(Qh, Kh, Vth, OP, Mb, Lb);

    combine<<<(int)(SD / 4 / 256), blk, 0, stream>>>(OP, Mb, Lb, AOh);

    gemm_out<<<dim3(DM / 128, SEQ / 64), blk, 0, stream>>>(AOh, woh, out);
}

// Round 10
// 222.055 us; speedup vs baseline: 1.6017x; 1.6017x over previous
//
#include <hip/hip_runtime.h>
#include <math.h>

#define SEQ 4096
#define DM  1024
#define NH  16
#define DH  64
#define NS  4      // k-splits per q-tile

typedef _Float16 h16;
typedef __attribute__((ext_vector_type(4))) _Float16 h16x4;
typedef __attribute__((ext_vector_type(8))) _Float16 h16x8;
typedef __attribute__((ext_vector_type(4))) float f32x4;

// async global->LDS, 16B per lane, dest = wave-uniform base + lane*16
__device__ __forceinline__ void gload_lds16(const h16* g, h16* l) {
    __builtin_amdgcn_global_load_lds(
        (const __attribute__((address_space(1))) void*)g,
        (__attribute__((address_space(3))) void*)l, 16, 0, 0);
}

// ---------------------------------------------------------------------------
// Single fused fp32 -> fp16 conversion for x + all 4 weights.
// ---------------------------------------------------------------------------
__global__ __launch_bounds__(256) void cvt_all(const float* __restrict__ x,
                                               const float* __restrict__ wq,
                                               const float* __restrict__ wk,
                                               const float* __restrict__ wv,
                                               const float* __restrict__ wo,
                                               h16* __restrict__ dst) {
    const size_t SD4 = (size_t)SEQ * DM / 4;   // 1M float4s
    const size_t DD4 = (size_t)DM * DM / 4;    // 256K float4s
    const size_t i = (size_t)blockIdx.x * 256 + threadIdx.x;
    const float* src;
    size_t off;
    if (i < SD4) { src = x; off = i; }
    else {
        const size_t j = i - SD4;
        const int wsel = (int)(j >> 18);       // DD4 = 2^18
        off = j & (DD4 - 1);
        src = (wsel == 0) ? wq : (wsel == 1) ? wk : (wsel == 2) ? wv : wo;
    }
    const float4 v = ((const float4*)src)[off];
    h16x4 o = { (h16)v.x, (h16)v.y, (h16)v.z, (h16)v.w };
    ((h16x4*)dst)[i] = o;
}

// ---------------------------------------------------------------------------
// m97-style MFMA GEMM: 128x128 tile, BK=64 (two 32-slabs), global_load_lds
// width-16 staging into unpadded GT=32 layout. 4 waves, 4x4 frags.
// Layouts: Q/K plain [SEQ][DM] (scaled Q), V^T [DM][SEQ].
// ---------------------------------------------------------------------------
#define GT 32

// z = 0,1,2 -> Q (scaled), K, V^T outputs
__global__ __launch_bounds__(256) void gemm_qkv(const h16* __restrict__ xh,
                                                const h16* __restrict__ Wq,
                                                const h16* __restrict__ Wk,
                                                const h16* __restrict__ Wv,
                                                h16* __restrict__ Qh,
                                                h16* __restrict__ Kh,
                                                h16* __restrict__ Vth,
                                                float scl) {
    __shared__ h16 As[2][128 * GT];
    __shared__ h16 Bs[2][128 * GT];

    const int z    = blockIdx.z;
    const h16* B   = (z == 0) ? Wq : (z == 1) ? Wk : Wv;
    const int t    = threadIdx.x;
    const int lane = t & 63;
    const int w    = t >> 6;
    const int wm   = (w >> 1) * 64;
    const int wn   = (w & 1) * 64;
    const int l15  = lane & 15;
    const int lq   = lane >> 4;
    const int lq8  = lq * 8;
    const int m0   = blockIdx.y * 128;
    const int n0   = blockIdx.x * 128;
    const int K = DM, M = SEQ, N = DM;

    const int srow = w * 16 + (lane >> 2);
    const int scol = (lane & 3) * 8;
    const h16* pa0 = xh + (size_t)(m0 + srow) * K + scol;
    const h16* pa1 = xh + (size_t)(m0 + 64 + srow) * K + scol;
    const h16* pb0 = B  + (size_t)(n0 + srow) * K + scol;
    const h16* pb1 = B  + (size_t)(n0 + 64 + srow) * K + scol;

    f32x4 acc[4][4] = {};

    for (int k0 = 0; k0 < K; k0 += 64) {
        __syncthreads();
        #pragma unroll
        for (int s = 0; s < 2; ++s) {
            const int ko = k0 + s * 32;
            gload_lds16(pa0 + ko, &As[s][w * 512]);
            gload_lds16(pa1 + ko, &As[s][2048 + w * 512]);
            gload_lds16(pb0 + ko, &Bs[s][w * 512]);
            gload_lds16(pb1 + ko, &Bs[s][2048 + w * 512]);
        }
        __syncthreads();

        #pragma unroll
        for (int s = 0; s < 2; ++s) {
            h16x8 af[4], bf[4];
            #pragma unroll
            for (int i = 0; i < 4; ++i)
                af[i] = *(const h16x8*)&As[s][(wm + i * 16 + l15) * GT + lq8];
            #pragma unroll
            for (int j = 0; j < 4; ++j)
                bf[j] = *(const h16x8*)&Bs[s][(wn + j * 16 + l15) * GT + lq8];
            #pragma unroll
            for (int i = 0; i < 4; ++i)
                #pragma unroll
                for (int j = 0; j < 4; ++j)
                    acc[i][j] = __builtin_amdgcn_mfma_f32_16x16x32_f16(af[i], bf[j], acc[i][j], 0, 0, 0);
        }
    }

    const int cr = wm + lq * 4;
    const int cc = wn + l15;
    if (z == 2) {   // V^T: h16 [N][M], vectorized along M
        #pragma unroll
        for (int i = 0; i < 4; ++i)
            #pragma unroll
            for (int j = 0; j < 4; ++j) {
                const int gm0 = m0 + cr + i * 16;
                const int gn  = n0 + cc + j * 16;
                h16x4 v = { (h16)acc[i][j][0], (h16)acc[i][j][1],
                            (h16)acc[i][j][2], (h16)acc[i][j][3] };
                *(h16x4*)(Vth + (size_t)gn * M + gm0) = v;
            }
    } else {
        h16* Og = (z == 0) ? Qh : Kh;
        const float e = (z == 0) ? scl : 1.0f;
        #pragma unroll
        for (int i = 0; i < 4; ++i)
            #pragma unroll
            for (int j = 0; j < 4; ++j)
                #pragma unroll
                for (int r = 0; r < 4; ++r) {
                    const int gm = m0 + cr + i * 16 + r;
                    const int gn = n0 + cc + j * 16;
                    Og[(size_t)gm * N + gn] = (h16)(acc[i][j][r] * e);
                }
    }
}

// out[M][N] (f32) = AO (h16) @ Wo^T (h16). 64x128 tile -> grid 512 = 2/CU.
__global__ __launch_bounds__(256) void gemm_out(const h16* __restrict__ A,
                                                const h16* __restrict__ B,
                                                float* __restrict__ C) {
    __shared__ h16 As[2][64 * GT];
    __shared__ h16 Bs[2][128 * GT];

    const int t    = threadIdx.x;
    const int lane = t & 63;
    const int w    = t >> 6;
    const int wm   = (w >> 1) * 32;
    const int wn   = (w & 1) * 64;
    const int l15  = lane & 15;
    const int lq   = lane >> 4;
    const int lq8  = lq * 8;
    const int m0   = blockIdx.y * 64;
    const int n0   = blockIdx.x * 128;
    const int K = DM, N = DM;

    const int srow = w * 16 + (lane >> 2);
    const int scol = (lane & 3) * 8;
    const h16* pa0 = A + (size_t)(m0 + srow) * K + scol;
    const h16* pb0 = B + (size_t)(n0 + srow) * K + scol;
    const h16* pb1 = B + (size_t)(n0 + 64 + srow) * K + scol;

    f32x4 acc[2][4] = {};

    for (int k0 = 0; k0 < K; k0 += 64) {
        __syncthreads();
        #pragma unroll
        for (int s = 0; s < 2; ++s) {
            const int ko = k0 + s * 32;
            gload_lds16(pa0 + ko, &As[s][w * 512]);
            gload_lds16(pb0 + ko, &Bs[s][w * 512]);
            gload_lds16(pb1 + ko, &Bs[s][2048 + w * 512]);
        }
        __syncthreads();

        #pragma unroll
        for (int s = 0; s < 2; ++s) {
            h16x8 af[2], bf[4];
            #pragma unroll
            for (int i = 0; i < 2; ++i)
                af[i] = *(const h16x8*)&As[s][(wm + i * 16 + l15) * GT + lq8];
            #pragma unroll
            for (int j = 0; j < 4; ++j)
                bf[j] = *(const h16x8*)&Bs[s][(wn + j * 16 + l15) * GT + lq8];
            #pragma unroll
            for (int i = 0; i < 2; ++i)
                #pragma unroll
                for (int j = 0; j < 4; ++j)
                    acc[i][j] = __builtin_amdgcn_mfma_f32_16x16x32_f16(af[i], bf[j], acc[i][j], 0, 0, 0);
        }
    }

    const int cr = wm + lq * 4;
    const int cc = wn + l15;
    #pragma unroll
    for (int i = 0; i < 2; ++i)
        #pragma unroll
        for (int j = 0; j < 4; ++j)
            #pragma unroll
            for (int r = 0; r < 4; ++r)
                C[(size_t)(m0 + cr + i * 16 + r) * N + n0 + cc + j * 16] = acc[i][j][r];
}

// ---------------------------------------------------------------------------
// SPLIT-K MFMA flash attention (causal), S^T formulation, exp2 domain.
// Register-P PV; each wave owns two 16-q bands (q, q+64) of a 128-q block.
// THIS ROUND (vs r5 best-known):
//  1. SINGLE-buffered Ks/Vs (19456B LDS, r2's proven 2-barrier sync) ->
//     up to 4+ blocks/CU resident (was 2). The untested {128-q reuse x
//     high-occupancy} cell of the design matrix.
//  2. l computed via ones-MFMA: D = 1*P sums P over k ACROSS LANES in the
//     matrix pipe — removes 32 serial VALU adds/iter + the epilogue shfls.
//  3. Balanced max tree (dep depth 15 -> 4).
// ---------------------------------------------------------------------------
#define AST 80
#define VST 72

__global__ __launch_bounds__(256, 3) void flash_attn_split(
        const h16* __restrict__ Qg, const h16* __restrict__ Kg,
        const h16* __restrict__ Vt, h16* __restrict__ OP,
        float* __restrict__ Mb, float* __restrict__ Lb) {
    __shared__ h16 Ks[64 * AST];   // [k_local][d]
    __shared__ h16 Vs[64 * VST];   // [d][k_local]

    const int jq   = 31 - (int)blockIdx.y;   // big chunks dispatch first
    const int hh   = blockIdx.x;
    const int sp   = blockIdx.z;
    const int t    = threadIdx.x;
    const int lane = t & 63;
    const int w    = t >> 6;
    const int l15  = lane & 15;
    const int lq   = lane >> 4;
    const int lq8  = lq * 8;
    const int hc   = hh * DH;
    const int q0   = jq * 128;
    const int qa   = w * 16 + l15;           // local q within each 64-half
    const int diag1 = 2 * jq;                // diagonal k-tile of half 1
    const int diag2 = 2 * jq + 1;            // diagonal k-tile of half 2

    const int ntile = 2 * jq + 2;
    const int chunk = (ntile + NS - 1) / NS;
    const int kts   = sp * chunk;
    const int kte   = (kts + chunk < ntile) ? (kts + chunk) : ntile;

    const int r1 = t >> 3;             // 0..31
    const int r2 = r1 + 32;
    const int c1 = (t & 7) * 8;

    // Q fragments for both halves: direct global reads (one-time per block)
    const size_t qrow1 = (size_t)(q0 + qa) * DM + hc;
    const size_t qrow2 = (size_t)(q0 + 64 + qa) * DM + hc;
    h16x8 qf[2][2];
    qf[0][0] = *(const h16x8*)(Qg + qrow1 + lq8);
    qf[0][1] = *(const h16x8*)(Qg + qrow1 + 32 + lq8);
    qf[1][0] = *(const h16x8*)(Qg + qrow2 + lq8);
    qf[1][1] = *(const h16x8*)(Qg + qrow2 + 32 + lq8);

    float m_st[2] = { -1e30f, -1e30f };
    f32x4 lacc[2] = {};                  // l via ones-MFMA (k-sum in matrix pipe)
    f32x4 o[2][4] = {};
    const h16x4 one4 = { (h16)1.0f, (h16)1.0f, (h16)1.0f, (h16)1.0f };

    h16x8 kv1, kv2, vv1, vv2;            // single prefetch register set

    // preload first K/V tile of this split (kts*64 <= 3072: in-bounds)
    if (kts < kte) {
        const int kb0 = kts * 64;
        kv1 = *(const h16x8*)(Kg + (size_t)(kb0 + r1) * DM + hc + c1);
        kv2 = *(const h16x8*)(Kg + (size_t)(kb0 + r2) * DM + hc + c1);
        vv1 = *(const h16x8*)(Vt + (size_t)(hc + r1) * SEQ + kb0 + c1);
        vv2 = *(const h16x8*)(Vt + (size_t)(hc + r2) * SEQ + kb0 + c1);
    }

    for (int kt = kts; kt < kte; ++kt) {
        __syncthreads();   // prior tile's frag reads drained
        *(h16x8*)&Ks[r1 * AST + c1] = kv1;
        *(h16x8*)&Ks[r2 * AST + c1] = kv2;
        *(h16x8*)&Vs[r1 * VST + c1] = vv1;
        *(h16x8*)&Vs[r2 * VST + c1] = vv2;
        __syncthreads();   // published
        if (kt + 1 < kte) {   // prefetch next tile (covered by compute below)
            const int k0n = (kt + 1) * 64;
            kv1 = *(const h16x8*)(Kg + (size_t)(k0n + r1) * DM + hc + c1);
            kv2 = *(const h16x8*)(Kg + (size_t)(k0n + r2) * DM + hc + c1);
            vv1 = *(const h16x8*)(Vt + (size_t)(hc + r1) * SEQ + k0n + c1);
            vv2 = *(const h16x8*)(Vt + (size_t)(hc + r2) * SEQ + k0n + c1);
        }

        // ---- S^T = K Q^T for both q-halves; kf shared ----
        f32x4 s[2][4] = {};
        #pragma unroll
        for (int kc = 0; kc < 2; ++kc) {
            h16x8 kf[4];
            #pragma unroll
            for (int jj = 0; jj < 4; ++jj)
                kf[jj] = *(const h16x8*)&Ks[(jj * 16 + l15) * AST + kc * 32 + lq8];
            #pragma unroll
            for (int jj = 0; jj < 4; ++jj)
                s[0][jj] = __builtin_amdgcn_mfma_f32_16x16x32_f16(kf[jj], qf[0][kc], s[0][jj], 0, 0, 0);
            #pragma unroll
            for (int jj = 0; jj < 4; ++jj)
                s[1][jj] = __builtin_amdgcn_mfma_f32_16x16x32_f16(kf[jj], qf[1][kc], s[1][jj], 0, 0, 0);
        }

        // ---- causal masks (block-uniform outer branches) ----
        if (kt >= diag1) {   // half 1: partial at diag1, full beyond
            const int rel = (q0 + qa) - kt * 64;
            #pragma unroll
            for (int jj = 0; jj < 4; ++jj)
                #pragma unroll
                for (int r = 0; r < 4; ++r)
                    if ((jj * 16 + lq * 4 + r) > rel) s[0][jj][r] = -1e30f;
        }
        if (kt >= diag2) {   // half 2: partial at diag2 (last tile)
            const int rel = (q0 + 64 + qa) - kt * 64;
            #pragma unroll
            for (int jj = 0; jj < 4; ++jj)
                #pragma unroll
                for (int r = 0; r < 4; ++r)
                    if ((jj * 16 + lq * 4 + r) > rel) s[1][jj][r] = -1e30f;
        }

        // ---- online softmax (in-register), both halves ----
        h16x4 pk[2][4];
        #pragma unroll
        for (int h = 0; h < 2; ++h) {
            // balanced max tree (dep depth 4)
            const float a0 = fmaxf(fmaxf(s[h][0][0], s[h][0][1]), fmaxf(s[h][0][2], s[h][0][3]));
            const float a1 = fmaxf(fmaxf(s[h][1][0], s[h][1][1]), fmaxf(s[h][1][2], s[h][1][3]));
            const float a2 = fmaxf(fmaxf(s[h][2][0], s[h][2][1]), fmaxf(s[h][2][2], s[h][2][3]));
            const float a3 = fmaxf(fmaxf(s[h][3][0], s[h][3][1]), fmaxf(s[h][3][2], s[h][3][3]));
            float mx = fmaxf(fmaxf(a0, a1), fmaxf(a2, a3));
            mx = fmaxf(mx, __shfl_xor(mx, 16, 64));
            mx = fmaxf(mx, __shfl_xor(mx, 32, 64));
            // defer-max: rescale only when tile max grows by >5 (exp2 domain:
            // P bounded by 2^5, fp16-safe). mx uniform over a q-row's 4 lanes.
            if (mx > m_st[h] + 5.0f) {
                const float alpha = exp2f(m_st[h] - mx);
                m_st[h] = mx;
                #pragma unroll
                for (int r = 0; r < 4; ++r) lacc[h][r] *= alpha;
                #pragma unroll
                for (int jj = 0; jj < 4; ++jj)
                    #pragma unroll
                    for (int r = 0; r < 4; ++r)
                        o[h][jj][r] *= alpha;
            }
            #pragma unroll
            for (int jj = 0; jj < 4; ++jj) {
                const float p0 = exp2f(s[h][jj][0] - m_st[h]);
                const float p1 = exp2f(s[h][jj][1] - m_st[h]);
                const float p2 = exp2f(s[h][jj][2] - m_st[h]);
                const float p3 = exp2f(s[h][jj][3] - m_st[h]);
                pk[h][jj] = h16x4{ (h16)p0, (h16)p1, (h16)p2, (h16)p3 };
            }
            // l-sum rides the matrix pipe: D[i][q] = sum_k 1*P[k][q]
            #pragma unroll
            for (int jj = 0; jj < 4; ++jj)
                lacc[h] = __builtin_amdgcn_mfma_f32_16x16x16f16(one4, pk[h][jj], lacc[h], 0, 0, 0);
        }

        // ---- O^T += V^T P^T (16x16x16 MFMA); vf shared by both halves ----
        #pragma unroll
        for (int dd = 0; dd < 4; ++dd)
            #pragma unroll
            for (int jj = 0; jj < 4; ++jj) {
                const h16x4 vf = *(const h16x4*)&Vs[(dd * 16 + l15) * VST + jj * 16 + lq * 4];
                o[0][dd] = __builtin_amdgcn_mfma_f32_16x16x16f16(vf, pk[0][jj], o[0][dd], 0, 0, 0);
                o[1][dd] = __builtin_amdgcn_mfma_f32_16x16x16f16(vf, pk[1][jj], o[1][dd], 0, 0, 0);
            }
    }

    // ---- epilogue: write UNNORMALIZED partial O + (m, l), both halves ----
    // lacc rows are all identical (A == ones) -> element 0 is the full k-sum
    // for this lane's q column; no cross-lane fold needed.
    h16* const op = OP + (size_t)sp * SEQ * DM;
    #pragma unroll
    for (int h = 0; h < 2; ++h) {
        const int qg_row = q0 + h * 64 + qa;
        const size_t qg = (size_t)qg_row * DM + hc;
        #pragma unroll
        for (int jj = 0; jj < 4; ++jj) {
            h16x4 ov = { (h16)o[h][jj][0], (h16)o[h][jj][1],
                         (h16)o[h][jj][2], (h16)o[h][jj][3] };
            *(h16x4*)(op + qg + jj * 16 + lq * 4) = ov;
        }
        if (lq == 0) {   // one lane per q-row
            const size_t mi = ((size_t)sp * NH + hh) * SEQ + qg_row;
            Mb[mi] = m_st[h];
            Lb[mi] = lacc[h][0];
        }
    }
}

// ---------------------------------------------------------------------------
// Combine NS partials: O = sum_s w_s*O_s / sum_s w_s*l_s, w_s = exp2(m_s-m*).
// One thread per 4 d-columns of one q-row.
// ---------------------------------------------------------------------------
__global__ __launch_bounds__(256) void combine(const h16* __restrict__ OP,
                                               const float* __restrict__ Mb,
                                               const float* __restrict__ Lb,
                                               h16* __restrict__ AOh) {
    const int i  = blockIdx.x * 256 + threadIdx.x;   // 1M threads
    const int q  = i >> 8;
    const int c4 = (i & 255) * 4;
    const int hh = c4 >> 6;

    float ms[NS], ls[NS];
    float mstar = -1e30f;
    #pragma unroll
    for (int s = 0; s < NS; ++s) {
        const size_t mi = ((size_t)s * NH + hh) * SEQ + q;
        ms[s] = Mb[mi];
        ls[s] = Lb[mi];
        mstar = fmaxf(mstar, ms[s]);
    }
    float L = 0.0f;
    float acc[4] = {};
    #pragma unroll
    for (int s = 0; s < NS; ++s) {
        const float ws = exp2f(ms[s] - mstar);
        L += ls[s] * ws;
        const h16x4 ov = *(const h16x4*)(OP + (size_t)s * SEQ * DM + (size_t)q * DM + c4);
        acc[0] += ws * (float)ov[0];
        acc[1] += ws * (float)ov[1];
        acc[2] += ws * (float)ov[2];
        acc[3] += ws * (float)ov[3];
    }
    const float inv = 1.0f / L;
    h16x4 r = { (h16)(acc[0] * inv), (h16)(acc[1] * inv),
                (h16)(acc[2] * inv), (h16)(acc[3] * inv) };
    *(h16x4*)(AOh + (size_t)q * DM + c4) = r;
}

// ---------------------------------------------------------------------------
extern "C" void kernel_launch(void* const* d_in, const int* in_sizes, int n_in,
                              void* d_out, int out_size, void* d_ws, size_t ws_size,
                              hipStream_t stream) {
    const float* x  = (const float*)d_in[0];
    const float* Wq = (const float*)d_in[1];
    const float* Wk = (const float*)d_in[2];
    const float* Wv = (const float*)d_in[3];
    const float* Wo = (const float*)d_in[4];
    float* out = (float*)d_out;

    const size_t SD = (size_t)SEQ * DM;   // 4M
    const size_t DD = (size_t)DM * DM;    // 1M

    h16* xh  = (h16*)d_ws;                // cvt_all relies on this contiguity
    h16* wqh = xh + SD;
    h16* wkh = wqh + DD;
    h16* wvh = wkh + DD;
    h16* woh = wvh + DD;
    h16* Qh  = woh + DD;
    h16* Kh  = Qh + SD;
    h16* Vth = Kh + SD;                   // transposed: [DM][SEQ]
    h16* AOh = Vth + SD;
    h16* OP  = AOh + SD;                  // NS partial O buffers
    float* Mb = (float*)(OP + (size_t)NS * SD);
    float* Lb = Mb + (size_t)NS * NH * SEQ;

    const dim3 blk(256);

    cvt_all<<<(int)((SD + 4 * DD) / 4 / 256), blk, 0, stream>>>(x, Wq, Wk, Wv, Wo, xh);

    // Q pre-scaled by 1/sqrt(DH) * log2(e) for the exp2-domain softmax
    const float SCL = 0.125f * 1.44269504088896340736f;

    gemm_qkv<<<dim3(DM / 128, SEQ / 128, 3), blk, 0, stream>>>(
        xh, wqh, wkh, wvh, Qh, Kh, Vth, SCL);

    flash_attn_split<<<dim3(NH, 32, NS), blk, 0, stream>>>(Qh, Kh, Vth, OP, Mb, Lb);

    combine<<<(int)(SD / 4 / 256), blk, 0, stream>>>(OP, Mb, Lb, AOh);

    gemm_out<<<dim3(DM / 128, SEQ / 64), blk, 0, stream>>>(AOh, woh, out);
}